// Round 5
// baseline (276.227 us; speedup 1.0000x reference)
//
#include <hip/hip_runtime.h>
#include <hip/hip_bf16.h>
#include <math.h>

#define DIMSZ 1024
#define HEADS 16
#define DHEAD 64
#define NSEQ  2048
#define BATCH 2
#define ROWS  (BATCH*NSEQ)        // 4096
#define SCALE 0.125f
#define LOG2E 1.4426950408889634f

typedef __attribute__((ext_vector_type(8))) short short8;
typedef __attribute__((ext_vector_type(4))) float floatx4;

#define MFMA16(a,b,c) __builtin_amdgcn_mfma_f32_16x16x32_bf16(a,b,c,0,0,0)

__device__ __forceinline__ void gl2lds16(const void* g, void* l) {
    __builtin_amdgcn_global_load_lds(
        (const __attribute__((address_space(1))) unsigned int*)g,
        (__attribute__((address_space(3))) unsigned int*)l, 16, 0, 0);
}

// branch-free RNE f32->bf16 (finite values only)
__device__ __forceinline__ unsigned short bf16r(float a) {
    unsigned u = __float_as_uint(a);
    u += 0x7fff + ((u >> 16) & 1);
    return (unsigned short)(u >> 16);
}
__device__ __forceinline__ unsigned pack_bf16(float a, float b) {
    unsigned ua = __float_as_uint(a), ub = __float_as_uint(b);
    ua += 0x7fff + ((ua >> 16) & 1);
    ub += 0x7fff + ((ub >> 16) & 1);
    return (ua >> 16) | (ub & 0xffff0000u);
}
__device__ __forceinline__ float2 bf2f(unsigned u) {
    float2 r;
    r.x = __uint_as_float(u << 16);
    r.y = __uint_as_float(u & 0xffff0000u);
    return r;
}
__device__ __forceinline__ float fexp2(float x) {
#if __has_builtin(__builtin_amdgcn_exp2f)
    return __builtin_amdgcn_exp2f(x);
#else
    return exp2f(x);
#endif
}
__device__ __forceinline__ float fsin_rev(float x) {
#if __has_builtin(__builtin_amdgcn_sinf)
    return __builtin_amdgcn_sinf(x);
#else
    return __sinf(x * 6.28318530717958647692f);
#endif
}
__device__ __forceinline__ float fcos_rev(float x) {
#if __has_builtin(__builtin_amdgcn_cosf)
    return __builtin_amdgcn_cosf(x);
#else
    return __cosf(x * 6.28318530717958647692f);
#endif
}

// ---------------------------------------------------------------------------
// K0: transposes fp32 -> bf16: w_qkv (1024x3072) -> (3072x1024),
// w_out (1024x1024) -> (1024x1024), and [w_mix|w_gates] (1024x16 each)
// -> stacked wmgT (32x1024).  bx: [0,96) qkv, [96,128) out, 128 = mix/gates
// ---------------------------------------------------------------------------
__global__ __launch_bounds__(256) void transpose_all_kernel(
    const float* __restrict__ w_qkv, const float* __restrict__ w_out,
    const float* __restrict__ w_mix, const float* __restrict__ w_gates,
    unsigned short* __restrict__ wqkvT, unsigned short* __restrict__ woutT,
    unsigned short* __restrict__ wmgT)
{
    __shared__ float t[32][33];
    const int tx = threadIdx.x & 31, tyy = threadIdx.x >> 5;
    const int bx = blockIdx.x;
    const int k0 = blockIdx.y * 32;
    if (bx < 128) {
        const float* src;
        unsigned short* dst;
        int N, n0;
        if (bx < 96) { src = w_qkv; dst = wqkvT; N = 3*DIMSZ; n0 = bx*32; }
        else         { src = w_out; dst = woutT; N = DIMSZ;   n0 = (bx-96)*32; }
        #pragma unroll
        for (int i = 0; i < 4; i++)
            t[tyy*4 + i][tx] = src[(size_t)(k0 + tyy*4 + i)*N + n0 + tx];
        __syncthreads();
        #pragma unroll
        for (int i = 0; i < 4; i++)
            dst[(size_t)(n0 + tyy*4 + i)*DIMSZ + k0 + tx] = bf16r(t[tx][tyy*4 + i]);
    } else {
        // virtual 1024x32 src = [w_mix | w_gates]
        #pragma unroll
        for (int i = 0; i < 4; i++) {
            const int kk = k0 + tyy*4 + i;
            t[tyy*4 + i][tx] = (tx < 16) ? w_mix[kk*16 + tx]
                                         : w_gates[kk*16 + (tx - 16)];
        }
        __syncthreads();
        #pragma unroll
        for (int i = 0; i < 4; i++)
            wmgT[(size_t)(tyy*4 + i)*DIMSZ + k0 + tx] = bf16r(t[tx][tyy*4 + i]);
    }
}

// ---------------------------------------------------------------------------
// K1: RMSNorm -> bf16 xn (pure streaming now)
// ---------------------------------------------------------------------------
__global__ __launch_bounds__(256) void rmsnorm_kernel(
    const float* __restrict__ x, const float* __restrict__ gamma,
    unsigned short* __restrict__ xnb)
{
    const int row = blockIdx.x;
    const int tid = threadIdx.x;
    __shared__ float wred[4];

    const float4 xv = ((const float4*)(x + (size_t)row * DIMSZ))[tid];
    float ss = xv.x*xv.x + xv.y*xv.y + xv.z*xv.z + xv.w*xv.w;
    #pragma unroll
    for (int off = 1; off < 64; off <<= 1) ss += __shfl_xor(ss, off);
    if ((tid & 63) == 0) wred[tid >> 6] = ss;
    __syncthreads();
    const float total = wred[0] + wred[1] + wred[2] + wred[3];
    const float inv = 32.0f / fmaxf(sqrtf(total), 1e-12f);
    const float4 gv = ((const float4*)gamma)[tid];
    uint2 pk;
    pk.x = pack_bf16(xv.x * inv * gv.x, xv.y * inv * gv.y);
    pk.y = pack_bf16(xv.z * inv * gv.z, xv.w * inv * gv.w);
    ((uint2*)(xnb + (size_t)row * DIMSZ))[tid] = pk;
}

// ---------------------------------------------------------------------------
// K1b: mix/gates = sigmoid(xn @ [w_mix|w_gates] + b)  via small MFMA GEMM
// M=4096, N=32, K=1024.  128-row tile, 32 blocks.
// ---------------------------------------------------------------------------
__global__ __launch_bounds__(256) void mix_gates_mfma(
    const unsigned short* __restrict__ A, const unsigned short* __restrict__ WG,
    const float* __restrict__ b_mix, const float* __restrict__ b_gates,
    float* __restrict__ mixo, float* __restrict__ gateso)
{
    __shared__ short As[128*32];
    __shared__ short Bs[32*32];
    const int tid = threadIdx.x;
    const int wv = tid >> 6, lane = tid & 63;
    const int g = lane >> 4, c = lane & 15;
    const int bm = blockIdx.x * 128;

    floatx4 acc[2][2];
    #pragma unroll
    for (int mt = 0; mt < 2; mt++)
        #pragma unroll
        for (int nt = 0; nt < 2; nt++) acc[mt][nt] = (floatx4){0.f,0.f,0.f,0.f};

    for (int k0 = 0; k0 < DIMSZ; k0 += 32) {
        __syncthreads();
        #pragma unroll
        for (int r = 0; r < 2; r++) {
            const int ch = tid + 256*r;
            const int row = ch >> 2, cc = ch & 3;
            gl2lds16(A + (size_t)(bm + row)*DIMSZ + k0 + cc*8, (void*)(As + ch*8));
        }
        if (tid < 128)
            gl2lds16(WG + (size_t)(tid >> 2)*DIMSZ + k0 + (tid & 3)*8, (void*)(Bs + tid*8));
        __syncthreads();
        short8 af[2], bf[2];
        #pragma unroll
        for (int mt = 0; mt < 2; mt++) af[mt] = *(const short8*)(As + (wv*32 + mt*16 + c)*32 + g*8);
        #pragma unroll
        for (int nt = 0; nt < 2; nt++) bf[nt] = *(const short8*)(Bs + (nt*16 + c)*32 + g*8);
        #pragma unroll
        for (int mt = 0; mt < 2; mt++)
            #pragma unroll
            for (int nt = 0; nt < 2; nt++)
                acc[mt][nt] = MFMA16(af[mt], bf[nt], acc[mt][nt]);
    }
    const float bm_c = b_mix[c], bg_c = b_gates[c];
    #pragma unroll
    for (int mt = 0; mt < 2; mt++)
        #pragma unroll
        for (int r2 = 0; r2 < 4; r2++) {
            const int row = bm + wv*32 + mt*16 + g*4 + r2;
            const float lm = acc[mt][0][r2] + bm_c;
            const float lg = acc[mt][1][r2] + bg_c;
            mixo[(size_t)row*HEADS + c]   = 1.0f / (1.0f + fexp2(-lm * LOG2E));
            gateso[(size_t)row*HEADS + c] = 1.0f / (1.0f + fexp2(-lg * LOG2E));
        }
}

// ---------------------------------------------------------------------------
// K2: bf16 MFMA GEMM xn(4096x1024) @ wqkvT(3072x1024)^T
//     q,k -> bf16 (b,h,n,d) via LDS-transpose vectorized epilogue;
//     v -> out1 fp32 (= original_values), scalar stores
// ---------------------------------------------------------------------------
__global__ __launch_bounds__(256) void gemm_qkv_mfma(
    const unsigned short* __restrict__ A, const unsigned short* __restrict__ BT,
    unsigned short* __restrict__ qb, unsigned short* __restrict__ kb,
    float* __restrict__ vb)
{
    __shared__ short As[128*32];
    __shared__ short Bs[128*32];
    const int tid = threadIdx.x;
    const int wv = tid >> 6, lane = tid & 63;
    const int g = lane >> 4, c = lane & 15;
    const int wm = wv >> 1, wn = wv & 1;
    const int bm = blockIdx.y * 128, bn = blockIdx.x * 128;

    floatx4 acc[4][4];
    #pragma unroll
    for (int mt = 0; mt < 4; mt++)
        #pragma unroll
        for (int nt = 0; nt < 4; nt++) acc[mt][nt] = (floatx4){0.f,0.f,0.f,0.f};

    for (int k0 = 0; k0 < DIMSZ; k0 += 32) {
        __syncthreads();
        #pragma unroll
        for (int r = 0; r < 2; r++) {
            const int ch = tid + 256*r;
            const int row = ch >> 2, cc = ch & 3;
            gl2lds16(A  + (size_t)(bm + row)*DIMSZ + k0 + cc*8, (void*)(As + ch*8));
            gl2lds16(BT + (size_t)(bn + row)*DIMSZ + k0 + cc*8, (void*)(Bs + ch*8));
        }
        __syncthreads();
        short8 af[4], bf[4];
        #pragma unroll
        for (int mt = 0; mt < 4; mt++) af[mt] = *(const short8*)(As + (wm*64 + mt*16 + c)*32 + g*8);
        #pragma unroll
        for (int nt = 0; nt < 4; nt++) bf[nt] = *(const short8*)(Bs + (wn*64 + nt*16 + c)*32 + g*8);
        #pragma unroll
        for (int mt = 0; mt < 4; mt++)
            #pragma unroll
            for (int nt = 0; nt < 4; nt++)
                acc[mt][nt] = MFMA16(af[mt], bf[nt], acc[mt][nt]);
    }
    __syncthreads();   // As reuse below must wait for all waves' last ds_reads
    const int i3 = bn >> 10;
    const int nb = bn - (i3 << 10);
    if (i3 < 2) {
        unsigned short* dst = (i3 == 0) ? qb : kb;
        short* wbuf = As + wv*1152;           // 16 rows x stride 72
        const int rd_row = lane >> 2, seg = lane & 3;
        #pragma unroll
        for (int mt = 0; mt < 4; mt++) {
            #pragma unroll
            for (int nt = 0; nt < 4; nt++)
                #pragma unroll
                for (int r2 = 0; r2 < 4; r2++)
                    wbuf[(g*4 + r2)*72 + nt*16 + c] = (short)bf16r(acc[mt][nt][r2]);
            __builtin_amdgcn_s_waitcnt(0xc07f);  // lgkmcnt(0), wave-private
            const uint4 v0 = *(const uint4*)&wbuf[rd_row*72 + seg*16];
            const uint4 v1 = *(const uint4*)&wbuf[rd_row*72 + seg*16 + 8];
            const int row = bm + wm*64 + mt*16 + rd_row;
            const int col = nb + wn*64 + seg*16;
            const int hh = col >> 6, dd = col & 63;
            const int bb2 = row >> 11, pos = row & 2047;
            unsigned short* dp = dst + (((size_t)(bb2*HEADS + hh)*NSEQ) + pos)*DHEAD + dd;
            *(uint4*)dp = v0;
            *(uint4*)(dp + 8) = v1;
            __builtin_amdgcn_s_waitcnt(0xc07f);  // reads done before next mt overwrite
        }
    } else {
        #pragma unroll
        for (int mt = 0; mt < 4; mt++)
            #pragma unroll
            for (int nt = 0; nt < 4; nt++)
                #pragma unroll
                for (int r2 = 0; r2 < 4; r2++) {
                    const int row = bm + wm*64 + mt*16 + g*4 + r2;
                    const int col = nb + wn*64 + nt*16 + c;
                    const int hh = col >> 6, dd = col & 63;
                    const int bb2 = row >> 11, pos = row & 2047;
                    vb[(((size_t)(bb2*HEADS + hh)*NSEQ) + pos)*DHEAD + dd] = acc[mt][nt][r2];
                }
    }
}

// ---------------------------------------------------------------------------
// K3: RoPE(q,k) bf16 in-place (q gets SCALE*LOG2E folded in);
//     v blend (fp32 out1 + vres) -> bf16 V^T
// ---------------------------------------------------------------------------
__global__ __launch_bounds__(256) void rope_blend_kernel2(
    unsigned short* __restrict__ q, unsigned short* __restrict__ k,
    const float* __restrict__ vorig, const float* __restrict__ vres,
    const float* __restrict__ mixb, unsigned short* __restrict__ vT)
{
    __shared__ unsigned short vt[64*72];
    const int tid = threadIdx.x;
    const int bh = blockIdx.y, bb = bh >> 4, h = bh & 15;
    const int p0 = blockIdx.x * 64;
    {
        const int pr = tid >> 2, d0 = (tid & 3) * 16;
        const int pos = p0 + pr;
        const size_t base = ((size_t)bh*NSEQ + pos)*DHEAD + d0;

        uint4 qr0 = *(uint4*)(q + base), qr1 = *(uint4*)(q + base + 8);
        uint4 kr0 = *(uint4*)(k + base), kr1 = *(uint4*)(k + base + 8);
        unsigned qw[8] = {qr0.x, qr0.y, qr0.z, qr0.w, qr1.x, qr1.y, qr1.z, qr1.w};
        unsigned kw[8] = {kr0.x, kr0.y, kr0.z, kr0.w, kr1.x, kr1.y, kr1.z, kr1.w};
        const float QSC = SCALE * LOG2E;
        const float posf = (float)pos;
        #pragma unroll
        for (int j = 0; j < 8; j++) {
            const float pf = (float)((d0 >> 1) + j);
            const float rev = posf * fexp2(-pf * 0.41524101186092029f
                                           - 2.6514961294723187f);
            const float rf = rev - floorf(rev);
            const float sn = fsin_rev(rf);
            const float cs = fcos_rev(rf);
            float2 qv = bf2f(qw[j]);
            float2 kv = bf2f(kw[j]);
            const float q1 = qv.x*cs - qv.y*sn, q2 = qv.x*sn + qv.y*cs;
            const float k1 = kv.x*cs - kv.y*sn, k2 = kv.x*sn + kv.y*cs;
            qw[j] = pack_bf16(q1*QSC, q2*QSC);
            kw[j] = pack_bf16(k1, k2);
        }
        *(uint4*)(q + base)     = *(uint4*)(qw + 0);
        *(uint4*)(q + base + 8) = *(uint4*)(qw + 4);
        *(uint4*)(k + base)     = *(uint4*)(kw + 0);
        *(uint4*)(k + base + 8) = *(uint4*)(kw + 4);

        float vv[16], vr[16];
        #pragma unroll
        for (int i = 0; i < 4; i++) {
            *(float4*)(vv + i*4) = *(const float4*)(vorig + base + i*4);
            *(float4*)(vr + i*4) = *(const float4*)(vres + base + i*4);
        }
        const float mx = mixb[((size_t)(bb*NSEQ + pos))*HEADS + h];
        #pragma unroll
        for (int j = 0; j < 8; j++) {
            const float b0 = vv[2*j]*(1.f-mx)   + vr[2*j]*mx;
            const float b1 = vv[2*j+1]*(1.f-mx) + vr[2*j+1]*mx;
            vt[pr*72 + d0 + 2*j]     = bf16r(b0);
            vt[pr*72 + d0 + 2*j + 1] = bf16r(b1);
        }
    }
    __syncthreads();
    {
        const int dd = tid >> 2, c0 = (tid & 3) * 16;
        unsigned o[8];
        #pragma unroll
        for (int j = 0; j < 8; j++) {
            const unsigned a  = vt[(c0 + 2*j)*72 + dd];
            const unsigned b2 = vt[(c0 + 2*j + 1)*72 + dd];
            o[j] = a | (b2 << 16);
        }
        unsigned short* dst = vT + ((size_t)bh*DHEAD + dd)*NSEQ + p0 + c0;
        *(uint4*)(dst)     = *(uint4*)(o + 0);
        *(uint4*)(dst + 8) = *(uint4*)(o + 4);
    }
}

// ---------------------------------------------------------------------------
// K4: MFMA flash attention, in-block split-K.
// 512 threads = 8 waves: wq = w&3 (32 q-rows each), s = w>>2 (K half).
// Q-tile 128 rows; each iter stages a PAIR of K/V 64-tiles (one per half).
// No online max (exp2 domain, q pre-scaled). Partials combine via LDS.
// LDS 64KB: KV 32K (Kt[2]+Vt[2]) + Ps 32K  ->  2 blocks/CU, 50% occupancy.
// ---------------------------------------------------------------------------
__global__ __launch_bounds__(512) void attn_mfma_kernel(
    const unsigned short* __restrict__ qg,   // (32,2048,64) bf16, * SCALE*LOG2E
    const unsigned short* __restrict__ kg,   // (32,2048,64) bf16
    const unsigned short* __restrict__ vT,   // (32,64,2048) bf16
    const float* __restrict__ gates,         // (4096,16)
    unsigned short* __restrict__ outp)       // (4096,1024) bf16
{
    __shared__ short KV[16384];    // Kt = KV[0:8192) (2 tiles), Vt = KV[8192:)
    __shared__ short Ps[16384];    // 8 waves x 32x64

    short* Kt = KV;
    short* Vt = KV + 8192;

    const int tid = threadIdx.x;
    const int w = tid >> 6, lane = tid & 63;
    const int wq = w & 3, s = w >> 2;
    const int g = lane >> 4, c = lane & 15;
    const int bh = blockIdx.y, bb = bh >> 4, h = bh & 15;
    const int q0 = blockIdx.x * 128;

    short8 qf[2][2];
    #pragma unroll
    for (int mt = 0; mt < 2; mt++)
        #pragma unroll
        for (int kb = 0; kb < 2; kb++)
            qf[mt][kb] = *(const short8*)(qg + ((size_t)bh*NSEQ + q0 + wq*32 + mt*16 + c)*DHEAD + kb*32 + g*8);

    floatx4 O[2][4];
    #pragma unroll
    for (int mt = 0; mt < 2; mt++)
        #pragma unroll
        for (int nt = 0; nt < 4; nt++) O[mt][nt] = (floatx4){0.f,0.f,0.f,0.f};
    float lsum[2] = {0.f, 0.f};

    short* PsW = Ps + w * 2048;
    short* Kts = Kt + s * 4096;
    short* Vts = Vt + s * 4096;
    const unsigned short* kbase = kg + (size_t)bh*NSEQ*DHEAD;
    const unsigned short* vbase = vT + (size_t)bh*DHEAD*NSEQ;

    for (int kt2 = 0; kt2 < 16; kt2++) {
        __syncthreads();
        #pragma unroll
        for (int r = 0; r < 2; r++) {
            const int ch = tid + 512*r;          // 0..1023
            const int t  = ch >> 9;              // which K-half tile
            const int cw = ch & 511;
            const int row = cw >> 3;
            const int u = (cw & 7) ^ (row & 7);
            const int ktile = kt2 + 16*t;
            gl2lds16(kbase + (size_t)(ktile*64 + row)*DHEAD + u*8, (void*)(Kt + t*4096 + cw*8));
            gl2lds16(vbase + (size_t)row*NSEQ + ktile*64 + u*8,   (void*)(Vt + t*4096 + cw*8));
        }
        __syncthreads();

        // hoisted K fragments
        short8 kfr[4][2];
        #pragma unroll
        for (int nt = 0; nt < 4; nt++) {
            const int rowk = nt*16 + c;
            #pragma unroll
            for (int kb = 0; kb < 2; kb++)
                kfr[nt][kb] = *(const short8*)(Kts + rowk*64 + (((kb*4 + g) ^ (rowk & 7)) * 8));
        }

        #pragma unroll
        for (int mt = 0; mt < 2; mt++) {
            const int rr = mt*16 + c;
            #pragma unroll
            for (int nt = 0; nt < 4; nt++) {
                floatx4 accS = (floatx4){0.f,0.f,0.f,0.f};
                #pragma unroll
                for (int kb = 0; kb < 2; kb++)
                    accS = MFMA16(kfr[nt][kb], qf[mt][kb], accS);
                const float p0 = fexp2(accS[0]);
                const float p1 = fexp2(accS[1]);
                const float p2 = fexp2(accS[2]);
                const float p3 = fexp2(accS[3]);
                lsum[mt] += (p0 + p1) + (p2 + p3);
                uint2 pk;
                pk.x = pack_bf16(p0, p1);
                pk.y = pack_bf16(p2, p3);
                *(uint2*)(PsW + rr*64 + (((nt*2 + (g >> 1)) ^ (rr & 7)) * 8) + (g & 1)*4) = pk;
            }
        }
        __builtin_amdgcn_s_waitcnt(0xc07f);   // lgkmcnt(0): Ps wave-private
        #pragma unroll
        for (int kb = 0; kb < 2; kb++) {
            short8 pf[2];
            #pragma unroll
            for (int mt = 0; mt < 2; mt++) {
                const int rr = mt*16 + c;
                pf[mt] = *(const short8*)(PsW + rr*64 + (((kb*4 + g) ^ (rr & 7)) * 8));
            }
            #pragma unroll
            for (int nt = 0; nt < 4; nt++) {
                const int rv = nt*16 + c;
                short8 vf = *(const short8*)(Vts + rv*64 + (((kb*4 + g) ^ (rv & 7)) * 8));
                #pragma unroll
                for (int mt = 0; mt < 2; mt++)
                    O[mt][nt] = MFMA16(pf[mt], vf, O[mt][nt]);
            }
        }
    }

    // ---- combine the two K-half partials (pure addition; no max rescale) ----
    __syncthreads();                       // everyone done reading KV/Ps
    float* cb = (float*)KV;                // 8192 floats: 4 wq x 2048
    float* lf = (float*)Ps;                // l partials
    if (s == 1) {
        #pragma unroll
        for (int mt = 0; mt < 2; mt++) {
            #pragma unroll
            for (int nt = 0; nt < 4; nt++)
                #pragma unroll
                for (int r2 = 0; r2 < 4; r2++)
                    cb[wq*2048 + ((mt*4 + nt)*4 + r2)*64 + lane] = O[mt][nt][r2];
            lf[wq*128 + mt*64 + lane] = lsum[mt];
        }
    }
    __syncthreads();
    if (s == 0) {
        #pragma unroll
        for (int mt = 0; mt < 2; mt++) {
            #pragma unroll
            for (int nt = 0; nt < 4; nt++)
                #pragma unroll
                for (int r2 = 0; r2 < 4; r2++)
                    O[mt][nt][r2] += cb[wq*2048 + ((mt*4 + nt)*4 + r2)*64 + lane];
            lsum[mt] += lf[wq*128 + mt*64 + lane];
        }
        #pragma unroll
        for (int mt = 0; mt < 2; mt++) {
            float l = lsum[mt];
            l += __shfl_xor(l, 16);
            l += __shfl_xor(l, 32);
            #pragma unroll
            for (int r2 = 0; r2 < 4; r2++) {
                const float lr = __shfl(l, g*4 + r2);
                const int rowg = q0 + wq*32 + mt*16 + g*4 + r2;
                const float gt = gates[((size_t)(bb*NSEQ + rowg))*HEADS + h];
                const float sc = gt / lr;
                unsigned short* op = outp + ((size_t)(bb*NSEQ + rowg))*DIMSZ + h*DHEAD + c;
                #pragma unroll
                for (int nt = 0; nt < 4; nt++)
                    op[nt*16] = bf16r(O[mt][nt][r2] * sc);
            }
        }
    }
}

// ---------------------------------------------------------------------------
// K5: bf16 MFMA GEMM attn_out(4096x1024) @ woutT(1024x1024)^T -> out0 fp32
// ---------------------------------------------------------------------------
__global__ __launch_bounds__(256) void gemm_out_mfma(
    const unsigned short* __restrict__ A, const unsigned short* __restrict__ BT,
    float* __restrict__ out0)
{
    __shared__ short As[128*32];
    __shared__ short Bs[128*32];
    const int tid = threadIdx.x;
    const int wv = tid >> 6, lane = tid & 63;
    const int g = lane >> 4, c = lane & 15;
    const int wm = wv >> 1, wn = wv & 1;
    const int bm = blockIdx.y * 128, bn = blockIdx.x * 128;

    floatx4 acc[4][4];
    #pragma unroll
    for (int mt = 0; mt < 4; mt++)
        #pragma unroll
        for (int nt = 0; nt < 4; nt++) acc[mt][nt] = (floatx4){0.f,0.f,0.f,0.f};

    for (int k0 = 0; k0 < DIMSZ; k0 += 32) {
        __syncthreads();
        #pragma unroll
        for (int r = 0; r < 2; r++) {
            const int ch = tid + 256*r;
            const int row = ch >> 2, cc = ch & 3;
            gl2lds16(A  + (size_t)(bm + row)*DIMSZ + k0 + cc*8, (void*)(As + ch*8));
            gl2lds16(BT + (size_t)(bn + row)*DIMSZ + k0 + cc*8, (void*)(Bs + ch*8));
        }
        __syncthreads();
        short8 af[4], bf[4];
        #pragma unroll
        for (int mt = 0; mt < 4; mt++) af[mt] = *(const short8*)(As + (wm*64 + mt*16 + c)*32 + g*8);
        #pragma unroll
        for (int nt = 0; nt < 4; nt++) bf[nt] = *(const short8*)(Bs + (wn*64 + nt*16 + c)*32 + g*8);
        #pragma unroll
        for (int mt = 0; mt < 4; mt++)
            #pragma unroll
            for (int nt = 0; nt < 4; nt++)
                acc[mt][nt] = MFMA16(af[mt], bf[nt], acc[mt][nt]);
    }
    #pragma unroll
    for (int mt = 0; mt < 4; mt++)
        #pragma unroll
        for (int nt = 0; nt < 4; nt++)
            #pragma unroll
            for (int r2 = 0; r2 < 4; r2++) {
                const int row = bm + wm*64 + mt*16 + g*4 + r2;
                const int col = bn + wn*64 + nt*16 + c;
                out0[(size_t)row*DIMSZ + col] = acc[mt][nt][r2];
            }
}

// ---------------------------------------------------------------------------
extern "C" void kernel_launch(void* const* d_in, const int* in_sizes, int n_in,
                              void* d_out, int out_size, void* d_ws, size_t ws_size,
                              hipStream_t stream) {
    const float* x       = (const float*)d_in[0];
    const float* vres    = (const float*)d_in[1];
    const float* gamma   = (const float*)d_in[2];
    const float* w_qkv   = (const float*)d_in[3];
    const float* w_mix   = (const float*)d_in[4];
    const float* b_mix   = (const float*)d_in[5];
    const float* w_gates = (const float*)d_in[6];
    const float* b_gates = (const float*)d_in[7];
    const float* w_out   = (const float*)d_in[8];

    float* out0 = (float*)d_out;                 // (2,2048,1024)
    float* out1 = out0 + (size_t)ROWS * DIMSZ;   // (2,16,2048,64) = original v

    char* ws = (char*)d_ws;
    unsigned short* xnb   = (unsigned short*)(ws);                    // 8 MB
    unsigned short* wqkvT = (unsigned short*)(ws + (8u<<20));         // 6 MB
    unsigned short* woutT = (unsigned short*)(ws + (14u<<20));        // 2 MB
    unsigned short* qb2   = (unsigned short*)(ws + (16u<<20));        // 8 MB
    unsigned short* kb2   = (unsigned short*)(ws + (24u<<20));        // 8 MB
    unsigned short* vT    = (unsigned short*)(ws + (32u<<20));        // 8 MB
    unsigned short* attnO = (unsigned short*)(ws + (40u<<20));        // 8 MB
    float*          mixb  = (float*)(ws + (48u<<20));                 // 256 KB
    float*          gatesb= (float*)(ws + (48u<<20) + 262144);        // 256 KB
    unsigned short* wmgT  = (unsigned short*)(ws + (49u<<20));        // 64 KB

    transpose_all_kernel<<<dim3(129, DIMSZ/32), 256, 0, stream>>>(
        w_qkv, w_out, w_mix, w_gates, wqkvT, woutT, wmgT);

    rmsnorm_kernel<<<ROWS, 256, 0, stream>>>(x, gamma, xnb);

    mix_gates_mfma<<<ROWS/128, 256, 0, stream>>>(
        xnb, wmgT, b_mix, b_gates, mixb, gatesb);

    gemm_qkv_mfma<<<dim3(3*DIMSZ/128, ROWS/128), 256, 0, stream>>>(
        xnb, wqkvT, qb2, kb2, out1);

    rope_blend_kernel2<<<dim3(NSEQ/64, BATCH*HEADS), 256, 0, stream>>>(
        qb2, kb2, out1, vres, mixb, vT);

    attn_mfma_kernel<<<dim3(NSEQ/128, BATCH*HEADS), 512, 0, stream>>>(
        qb2, kb2, vT, gatesb, attnO);

    gemm_out_mfma<<<dim3(DIMSZ/128, ROWS/128), 256, 0, stream>>>(
        attnO, woutT, out0);
}

// Round 6
// 259.696 us; speedup vs baseline: 1.0637x; 1.0637x over previous
//
#include <hip/hip_runtime.h>
#include <hip/hip_bf16.h>
#include <math.h>

#define DIMSZ 1024
#define HEADS 16
#define DHEAD 64
#define NSEQ  2048
#define BATCH 2
#define ROWS  (BATCH*NSEQ)        // 4096
#define SCALE 0.125f
#define LOG2E 1.4426950408889634f

typedef __attribute__((ext_vector_type(8))) short short8;
typedef __attribute__((ext_vector_type(4))) float floatx4;

#define MFMA16(a,b,c) __builtin_amdgcn_mfma_f32_16x16x32_bf16(a,b,c,0,0,0)

__device__ __forceinline__ void gl2lds16(const void* g, void* l) {
    __builtin_amdgcn_global_load_lds(
        (const __attribute__((address_space(1))) unsigned int*)g,
        (__attribute__((address_space(3))) unsigned int*)l, 16, 0, 0);
}

// branch-free RNE f32->bf16 (finite values only)
__device__ __forceinline__ unsigned short bf16r(float a) {
    unsigned u = __float_as_uint(a);
    u += 0x7fff + ((u >> 16) & 1);
    return (unsigned short)(u >> 16);
}
__device__ __forceinline__ unsigned pack_bf16(float a, float b) {
    unsigned ua = __float_as_uint(a), ub = __float_as_uint(b);
    ua += 0x7fff + ((ua >> 16) & 1);
    ub += 0x7fff + ((ub >> 16) & 1);
    return (ua >> 16) | (ub & 0xffff0000u);
}
__device__ __forceinline__ float2 bf2f(unsigned u) {
    float2 r;
    r.x = __uint_as_float(u << 16);
    r.y = __uint_as_float(u & 0xffff0000u);
    return r;
}
__device__ __forceinline__ float fexp2(float x) {
#if __has_builtin(__builtin_amdgcn_exp2f)
    return __builtin_amdgcn_exp2f(x);
#else
    return exp2f(x);
#endif
}
__device__ __forceinline__ float fsin_rev(float x) {
#if __has_builtin(__builtin_amdgcn_sinf)
    return __builtin_amdgcn_sinf(x);
#else
    return __sinf(x * 6.28318530717958647692f);
#endif
}
__device__ __forceinline__ float fcos_rev(float x) {
#if __has_builtin(__builtin_amdgcn_cosf)
    return __builtin_amdgcn_cosf(x);
#else
    return __cosf(x * 6.28318530717958647692f);
#endif
}

// ---------------------------------------------------------------------------
// K0: transposes fp32 -> bf16: w_qkv, w_out, and stacked [w_mix|w_gates]
// ---------------------------------------------------------------------------
__global__ __launch_bounds__(256) void transpose_all_kernel(
    const float* __restrict__ w_qkv, const float* __restrict__ w_out,
    const float* __restrict__ w_mix, const float* __restrict__ w_gates,
    unsigned short* __restrict__ wqkvT, unsigned short* __restrict__ woutT,
    unsigned short* __restrict__ wmgT)
{
    __shared__ float t[32][33];
    const int tx = threadIdx.x & 31, tyy = threadIdx.x >> 5;
    const int bx = blockIdx.x;
    const int k0 = blockIdx.y * 32;
    if (bx < 128) {
        const float* src;
        unsigned short* dst;
        int N, n0;
        if (bx < 96) { src = w_qkv; dst = wqkvT; N = 3*DIMSZ; n0 = bx*32; }
        else         { src = w_out; dst = woutT; N = DIMSZ;   n0 = (bx-96)*32; }
        #pragma unroll
        for (int i = 0; i < 4; i++)
            t[tyy*4 + i][tx] = src[(size_t)(k0 + tyy*4 + i)*N + n0 + tx];
        __syncthreads();
        #pragma unroll
        for (int i = 0; i < 4; i++)
            dst[(size_t)(n0 + tyy*4 + i)*DIMSZ + k0 + tx] = bf16r(t[tx][tyy*4 + i]);
    } else {
        #pragma unroll
        for (int i = 0; i < 4; i++) {
            const int kk = k0 + tyy*4 + i;
            t[tyy*4 + i][tx] = (tx < 16) ? w_mix[kk*16 + tx]
                                         : w_gates[kk*16 + (tx - 16)];
        }
        __syncthreads();
        #pragma unroll
        for (int i = 0; i < 4; i++)
            wmgT[(size_t)(tyy*4 + i)*DIMSZ + k0 + tx] = bf16r(t[tx][tyy*4 + i]);
    }
}

// ---------------------------------------------------------------------------
// K1: RMSNorm -> bf16 xn
// ---------------------------------------------------------------------------
__global__ __launch_bounds__(256) void rmsnorm_kernel(
    const float* __restrict__ x, const float* __restrict__ gamma,
    unsigned short* __restrict__ xnb)
{
    const int row = blockIdx.x;
    const int tid = threadIdx.x;
    __shared__ float wred[4];

    const float4 xv = ((const float4*)(x + (size_t)row * DIMSZ))[tid];
    float ss = xv.x*xv.x + xv.y*xv.y + xv.z*xv.z + xv.w*xv.w;
    #pragma unroll
    for (int off = 1; off < 64; off <<= 1) ss += __shfl_xor(ss, off);
    if ((tid & 63) == 0) wred[tid >> 6] = ss;
    __syncthreads();
    const float total = wred[0] + wred[1] + wred[2] + wred[3];
    const float inv = 32.0f / fmaxf(sqrtf(total), 1e-12f);
    const float4 gv = ((const float4*)gamma)[tid];
    uint2 pk;
    pk.x = pack_bf16(xv.x * inv * gv.x, xv.y * inv * gv.y);
    pk.y = pack_bf16(xv.z * inv * gv.z, xv.w * inv * gv.w);
    ((uint2*)(xnb + (size_t)row * DIMSZ))[tid] = pk;
}

// ---------------------------------------------------------------------------
// K1b: mix/gates = sigmoid(xn @ [w_mix|w_gates] + b) via small MFMA GEMM
// ---------------------------------------------------------------------------
__global__ __launch_bounds__(256) void mix_gates_mfma(
    const unsigned short* __restrict__ A, const unsigned short* __restrict__ WG,
    const float* __restrict__ b_mix, const float* __restrict__ b_gates,
    float* __restrict__ mixo, float* __restrict__ gateso)
{
    __shared__ short As[128*32];
    __shared__ short Bs[32*32];
    const int tid = threadIdx.x;
    const int wv = tid >> 6, lane = tid & 63;
    const int g = lane >> 4, c = lane & 15;
    const int bm = blockIdx.x * 128;

    floatx4 acc[2][2];
    #pragma unroll
    for (int mt = 0; mt < 2; mt++)
        #pragma unroll
        for (int nt = 0; nt < 2; nt++) acc[mt][nt] = (floatx4){0.f,0.f,0.f,0.f};

    for (int k0 = 0; k0 < DIMSZ; k0 += 32) {
        __syncthreads();
        #pragma unroll
        for (int r = 0; r < 2; r++) {
            const int ch = tid + 256*r;
            const int row = ch >> 2, cc = ch & 3;
            gl2lds16(A + (size_t)(bm + row)*DIMSZ + k0 + cc*8, (void*)(As + ch*8));
        }
        if (tid < 128)
            gl2lds16(WG + (size_t)(tid >> 2)*DIMSZ + k0 + (tid & 3)*8, (void*)(Bs + tid*8));
        __syncthreads();
        short8 af[2], bf[2];
        #pragma unroll
        for (int mt = 0; mt < 2; mt++) af[mt] = *(const short8*)(As + (wv*32 + mt*16 + c)*32 + g*8);
        #pragma unroll
        for (int nt = 0; nt < 2; nt++) bf[nt] = *(const short8*)(Bs + (nt*16 + c)*32 + g*8);
        #pragma unroll
        for (int mt = 0; mt < 2; mt++)
            #pragma unroll
            for (int nt = 0; nt < 2; nt++)
                acc[mt][nt] = MFMA16(af[mt], bf[nt], acc[mt][nt]);
    }
    const float bm_c = b_mix[c], bg_c = b_gates[c];
    #pragma unroll
    for (int mt = 0; mt < 2; mt++)
        #pragma unroll
        for (int r2 = 0; r2 < 4; r2++) {
            const int row = bm + wv*32 + mt*16 + g*4 + r2;
            const float lm = acc[mt][0][r2] + bm_c;
            const float lg = acc[mt][1][r2] + bg_c;
            mixo[(size_t)row*HEADS + c]   = 1.0f / (1.0f + fexp2(-lm * LOG2E));
            gateso[(size_t)row*HEADS + c] = 1.0f / (1.0f + fexp2(-lg * LOG2E));
        }
}

// ---------------------------------------------------------------------------
// K2: bf16 MFMA GEMM xn(4096x1024) @ wqkvT(3072x1024)^T
// ---------------------------------------------------------------------------
__global__ __launch_bounds__(256) void gemm_qkv_mfma(
    const unsigned short* __restrict__ A, const unsigned short* __restrict__ BT,
    unsigned short* __restrict__ qb, unsigned short* __restrict__ kb,
    float* __restrict__ vb)
{
    __shared__ short As[128*32];
    __shared__ short Bs[128*32];
    const int tid = threadIdx.x;
    const int wv = tid >> 6, lane = tid & 63;
    const int g = lane >> 4, c = lane & 15;
    const int wm = wv >> 1, wn = wv & 1;
    const int bm = blockIdx.y * 128, bn = blockIdx.x * 128;

    floatx4 acc[4][4];
    #pragma unroll
    for (int mt = 0; mt < 4; mt++)
        #pragma unroll
        for (int nt = 0; nt < 4; nt++) acc[mt][nt] = (floatx4){0.f,0.f,0.f,0.f};

    for (int k0 = 0; k0 < DIMSZ; k0 += 32) {
        __syncthreads();
        #pragma unroll
        for (int r = 0; r < 2; r++) {
            const int ch = tid + 256*r;
            const int row = ch >> 2, cc = ch & 3;
            gl2lds16(A  + (size_t)(bm + row)*DIMSZ + k0 + cc*8, (void*)(As + ch*8));
            gl2lds16(BT + (size_t)(bn + row)*DIMSZ + k0 + cc*8, (void*)(Bs + ch*8));
        }
        __syncthreads();
        short8 af[4], bf[4];
        #pragma unroll
        for (int mt = 0; mt < 4; mt++) af[mt] = *(const short8*)(As + (wm*64 + mt*16 + c)*32 + g*8);
        #pragma unroll
        for (int nt = 0; nt < 4; nt++) bf[nt] = *(const short8*)(Bs + (wn*64 + nt*16 + c)*32 + g*8);
        #pragma unroll
        for (int mt = 0; mt < 4; mt++)
            #pragma unroll
            for (int nt = 0; nt < 4; nt++)
                acc[mt][nt] = MFMA16(af[mt], bf[nt], acc[mt][nt]);
    }
    __syncthreads();
    const int i3 = bn >> 10;
    const int nb = bn - (i3 << 10);
    if (i3 < 2) {
        unsigned short* dst = (i3 == 0) ? qb : kb;
        short* wbuf = As + wv*1152;           // 16 rows x stride 72
        const int rd_row = lane >> 2, seg = lane & 3;
        #pragma unroll
        for (int mt = 0; mt < 4; mt++) {
            #pragma unroll
            for (int nt = 0; nt < 4; nt++)
                #pragma unroll
                for (int r2 = 0; r2 < 4; r2++)
                    wbuf[(g*4 + r2)*72 + nt*16 + c] = (short)bf16r(acc[mt][nt][r2]);
            __builtin_amdgcn_s_waitcnt(0xc07f);
            const uint4 v0 = *(const uint4*)&wbuf[rd_row*72 + seg*16];
            const uint4 v1 = *(const uint4*)&wbuf[rd_row*72 + seg*16 + 8];
            const int row = bm + wm*64 + mt*16 + rd_row;
            const int col = nb + wn*64 + seg*16;
            const int hh = col >> 6, dd = col & 63;
            const int bb2 = row >> 11, pos = row & 2047;
            unsigned short* dp = dst + (((size_t)(bb2*HEADS + hh)*NSEQ) + pos)*DHEAD + dd;
            *(uint4*)dp = v0;
            *(uint4*)(dp + 8) = v1;
            __builtin_amdgcn_s_waitcnt(0xc07f);
        }
    } else {
        #pragma unroll
        for (int mt = 0; mt < 4; mt++)
            #pragma unroll
            for (int nt = 0; nt < 4; nt++)
                #pragma unroll
                for (int r2 = 0; r2 < 4; r2++) {
                    const int row = bm + wm*64 + mt*16 + g*4 + r2;
                    const int col = nb + wn*64 + nt*16 + c;
                    const int hh = col >> 6, dd = col & 63;
                    const int bb2 = row >> 11, pos = row & 2047;
                    vb[(((size_t)(bb2*HEADS + hh)*NSEQ) + pos)*DHEAD + dd] = acc[mt][nt][r2];
                }
    }
}

// ---------------------------------------------------------------------------
// K3: RoPE(q,k) bf16 in-place; v blend -> bf16 V^T
// ---------------------------------------------------------------------------
__global__ __launch_bounds__(256) void rope_blend_kernel2(
    unsigned short* __restrict__ q, unsigned short* __restrict__ k,
    const float* __restrict__ vorig, const float* __restrict__ vres,
    const float* __restrict__ mixb, unsigned short* __restrict__ vT)
{
    __shared__ unsigned short vt[64*72];
    const int tid = threadIdx.x;
    const int bh = blockIdx.y, bb = bh >> 4, h = bh & 15;
    const int p0 = blockIdx.x * 64;
    {
        const int pr = tid >> 2, d0 = (tid & 3) * 16;
        const int pos = p0 + pr;
        const size_t base = ((size_t)bh*NSEQ + pos)*DHEAD + d0;

        uint4 qr0 = *(uint4*)(q + base), qr1 = *(uint4*)(q + base + 8);
        uint4 kr0 = *(uint4*)(k + base), kr1 = *(uint4*)(k + base + 8);
        unsigned qw[8] = {qr0.x, qr0.y, qr0.z, qr0.w, qr1.x, qr1.y, qr1.z, qr1.w};
        unsigned kw[8] = {kr0.x, kr0.y, kr0.z, kr0.w, kr1.x, kr1.y, kr1.z, kr1.w};
        const float QSC = SCALE * LOG2E;
        const float posf = (float)pos;
        #pragma unroll
        for (int j = 0; j < 8; j++) {
            const float pf = (float)((d0 >> 1) + j);
            const float rev = posf * fexp2(-pf * 0.41524101186092029f
                                           - 2.6514961294723187f);
            const float rf = rev - floorf(rev);
            const float sn = fsin_rev(rf);
            const float cs = fcos_rev(rf);
            float2 qv = bf2f(qw[j]);
            float2 kv = bf2f(kw[j]);
            const float q1 = qv.x*cs - qv.y*sn, q2 = qv.x*sn + qv.y*cs;
            const float k1 = kv.x*cs - kv.y*sn, k2 = kv.x*sn + kv.y*cs;
            qw[j] = pack_bf16(q1*QSC, q2*QSC);
            kw[j] = pack_bf16(k1, k2);
        }
        *(uint4*)(q + base)     = *(uint4*)(qw + 0);
        *(uint4*)(q + base + 8) = *(uint4*)(qw + 4);
        *(uint4*)(k + base)     = *(uint4*)(kw + 0);
        *(uint4*)(k + base + 8) = *(uint4*)(kw + 4);

        float vv[16], vr[16];
        #pragma unroll
        for (int i = 0; i < 4; i++) {
            *(float4*)(vv + i*4) = *(const float4*)(vorig + base + i*4);
            *(float4*)(vr + i*4) = *(const float4*)(vres + base + i*4);
        }
        const float mx = mixb[((size_t)(bb*NSEQ + pos))*HEADS + h];
        #pragma unroll
        for (int j = 0; j < 8; j++) {
            const float b0 = vv[2*j]*(1.f-mx)   + vr[2*j]*mx;
            const float b1 = vv[2*j+1]*(1.f-mx) + vr[2*j+1]*mx;
            vt[pr*72 + d0 + 2*j]     = bf16r(b0);
            vt[pr*72 + d0 + 2*j + 1] = bf16r(b1);
        }
    }
    __syncthreads();
    {
        const int dd = tid >> 2, c0 = (tid & 3) * 16;
        unsigned o[8];
        #pragma unroll
        for (int j = 0; j < 8; j++) {
            const unsigned a  = vt[(c0 + 2*j)*72 + dd];
            const unsigned b2 = vt[(c0 + 2*j + 1)*72 + dd];
            o[j] = a | (b2 << 16);
        }
        unsigned short* dst = vT + ((size_t)bh*DHEAD + dd)*NSEQ + p0 + c0;
        *(uint4*)(dst)     = *(uint4*)(o + 0);
        *(uint4*)(dst + 8) = *(uint4*)(o + 4);
    }
}

// ---------------------------------------------------------------------------
// K4: MFMA flash attention, GRID split-K (2 halves), round-3 inner structure.
// Block = 256 thr (4 waves x 32 q-rows), Q-tile 128, 16 K-tiles per block.
// grid = (16 qtiles, 64 = bh*2) = 1024 blocks -> 4 blocks/CU, LDS 32KB.
// No online max; partials (O bf16, l fp32) combined by attn_combine_kernel.
// ---------------------------------------------------------------------------
__global__ __launch_bounds__(256) void attn_mfma_kernel(
    const unsigned short* __restrict__ qg,   // (32,2048,64) bf16, * SCALE*LOG2E
    const unsigned short* __restrict__ kg,   // (32,2048,64) bf16
    const unsigned short* __restrict__ vT,   // (32,64,2048) bf16
    unsigned short* __restrict__ Op0,        // (4096,1024) bf16 partial s=0
    unsigned short* __restrict__ Op1,        // (4096,1024) bf16 partial s=1
    float* __restrict__ lpart)               // (2,4096,16) fp32
{
    __shared__ short Kt[64*64];
    __shared__ short Vt[64*64];
    __shared__ short Ps[4*32*64];

    const int tid = threadIdx.x;
    const int w = tid >> 6, lane = tid & 63;
    const int g = lane >> 4, c = lane & 15;
    const int byy = blockIdx.y;
    const int bh = byy >> 1, s = byy & 1;
    const int bb = bh >> 4, h = bh & 15;
    const int q0 = blockIdx.x * 128;

    short8 qf[2][2];
    #pragma unroll
    for (int mt = 0; mt < 2; mt++)
        #pragma unroll
        for (int kb = 0; kb < 2; kb++)
            qf[mt][kb] = *(const short8*)(qg + ((size_t)bh*NSEQ + q0 + w*32 + mt*16 + c)*DHEAD + kb*32 + g*8);

    floatx4 O[2][4];
    #pragma unroll
    for (int mt = 0; mt < 2; mt++)
        #pragma unroll
        for (int nt = 0; nt < 4; nt++) O[mt][nt] = (floatx4){0.f,0.f,0.f,0.f};
    float lsum[2] = {0.f, 0.f};

    short* PsW = Ps + w * 2048;
    const unsigned short* kbase = kg + (size_t)bh*NSEQ*DHEAD;
    const unsigned short* vbase = vT + (size_t)bh*DHEAD*NSEQ;

    for (int i = 0; i < 16; i++) {
        const int kt = s*16 + i;
        __syncthreads();
        #pragma unroll
        for (int r = 0; r < 2; r++) {
            const int ch = tid + 256*r;
            const int row = ch >> 3;
            const int u = (ch & 7) ^ (row & 7);
            gl2lds16(kbase + (size_t)(kt*64 + row)*DHEAD + u*8, (void*)(Kt + ch*8));
            gl2lds16(vbase + (size_t)row*NSEQ + kt*64 + u*8,   (void*)(Vt + ch*8));
        }
        __syncthreads();

        // hoisted K fragments (shared across mt)
        short8 kfr[4][2];
        #pragma unroll
        for (int nt = 0; nt < 4; nt++) {
            const int rowk = nt*16 + c;
            #pragma unroll
            for (int kb = 0; kb < 2; kb++)
                kfr[nt][kb] = *(const short8*)(Kt + rowk*64 + (((kb*4 + g) ^ (rowk & 7)) * 8));
        }

        #pragma unroll
        for (int mt = 0; mt < 2; mt++) {
            const int rr = mt*16 + c;
            #pragma unroll
            for (int nt = 0; nt < 4; nt++) {
                floatx4 accS = (floatx4){0.f,0.f,0.f,0.f};
                #pragma unroll
                for (int kb = 0; kb < 2; kb++)
                    accS = MFMA16(kfr[nt][kb], qf[mt][kb], accS);
                const float p0 = fexp2(accS[0]);
                const float p1 = fexp2(accS[1]);
                const float p2 = fexp2(accS[2]);
                const float p3 = fexp2(accS[3]);
                lsum[mt] += (p0 + p1) + (p2 + p3);
                uint2 pk;
                pk.x = pack_bf16(p0, p1);
                pk.y = pack_bf16(p2, p3);
                *(uint2*)(PsW + rr*64 + (((nt*2 + (g >> 1)) ^ (rr & 7)) * 8) + (g & 1)*4) = pk;
            }
        }
        __builtin_amdgcn_s_waitcnt(0xc07f);   // lgkmcnt(0): Ps wave-private
        #pragma unroll
        for (int kb = 0; kb < 2; kb++) {
            short8 pf[2];
            #pragma unroll
            for (int mt = 0; mt < 2; mt++) {
                const int rr = mt*16 + c;
                pf[mt] = *(const short8*)(PsW + rr*64 + (((kb*4 + g) ^ (rr & 7)) * 8));
            }
            #pragma unroll
            for (int nt = 0; nt < 4; nt++) {
                const int rv = nt*16 + c;
                short8 vf = *(const short8*)(Vt + rv*64 + (((kb*4 + g) ^ (rv & 7)) * 8));
                #pragma unroll
                for (int mt = 0; mt < 2; mt++)
                    O[mt][nt] = MFMA16(pf[mt], vf, O[mt][nt]);
            }
        }
    }

    // epilogue: write bf16 O partial + fp32 l partial
    unsigned short* Op = s ? Op1 : Op0;
    #pragma unroll
    for (int mt = 0; mt < 2; mt++) {
        float l = lsum[mt];
        l += __shfl_xor(l, 16);
        l += __shfl_xor(l, 32);
        if (g == 0) {
            const int rowl = q0 + w*32 + mt*16 + c;
            lpart[((size_t)s*ROWS + bb*NSEQ + rowl)*HEADS + h] = l;
        }
        #pragma unroll
        for (int r2 = 0; r2 < 4; r2++) {
            const int rowg = q0 + w*32 + mt*16 + g*4 + r2;
            unsigned short* op = Op + ((size_t)(bb*NSEQ + rowg))*DIMSZ + h*DHEAD + c;
            #pragma unroll
            for (int nt = 0; nt < 4; nt++)
                op[nt*16] = bf16r(O[mt][nt][r2]);
        }
    }
}

// ---------------------------------------------------------------------------
// K4b: combine split-K partials: attnO = (O0+O1) * gate/(l0+l1), in place
// over Op0 (attnO aliases Op0). One thread per 8 elements.
// ---------------------------------------------------------------------------
__global__ __launch_bounds__(256) void attn_combine_kernel(
    const unsigned short* __restrict__ Op1, const float* __restrict__ lpart,
    const float* __restrict__ gates, unsigned short* __restrict__ attnO)
{
    const int idx = blockIdx.x * 256 + threadIdx.x;   // 524288
    const int row = idx >> 7;
    const int c8 = (idx & 127) * 8;
    const int h = c8 >> 6;
    const float l0 = lpart[(size_t)row*HEADS + h];
    const float l1 = lpart[((size_t)ROWS + row)*HEADS + h];
    const float gt = gates[(size_t)row*HEADS + h];
    const float sc = gt / (l0 + l1);
    const size_t base = (size_t)row*DIMSZ + c8;
    const uint4 a = *(const uint4*)(attnO + base);   // Op0 partial
    const uint4 b = *(const uint4*)(Op1 + base);
    const unsigned aw[4] = {a.x, a.y, a.z, a.w};
    const unsigned bw[4] = {b.x, b.y, b.z, b.w};
    unsigned o[4];
    #pragma unroll
    for (int j = 0; j < 4; j++) {
        const float2 fa = bf2f(aw[j]);
        const float2 fb = bf2f(bw[j]);
        o[j] = pack_bf16((fa.x + fb.x)*sc, (fa.y + fb.y)*sc);
    }
    *(uint4*)(attnO + base) = *(uint4*)o;
}

// ---------------------------------------------------------------------------
// K5: bf16 MFMA GEMM attn_out(4096x1024) @ woutT(1024x1024)^T -> out0 fp32
// ---------------------------------------------------------------------------
__global__ __launch_bounds__(256) void gemm_out_mfma(
    const unsigned short* __restrict__ A, const unsigned short* __restrict__ BT,
    float* __restrict__ out0)
{
    __shared__ short As[128*32];
    __shared__ short Bs[128*32];
    const int tid = threadIdx.x;
    const int wv = tid >> 6, lane = tid & 63;
    const int g = lane >> 4, c = lane & 15;
    const int wm = wv >> 1, wn = wv & 1;
    const int bm = blockIdx.y * 128, bn = blockIdx.x * 128;

    floatx4 acc[4][4];
    #pragma unroll
    for (int mt = 0; mt < 4; mt++)
        #pragma unroll
        for (int nt = 0; nt < 4; nt++) acc[mt][nt] = (floatx4){0.f,0.f,0.f,0.f};

    for (int k0 = 0; k0 < DIMSZ; k0 += 32) {
        __syncthreads();
        #pragma unroll
        for (int r = 0; r < 2; r++) {
            const int ch = tid + 256*r;
            const int row = ch >> 2, cc = ch & 3;
            gl2lds16(A  + (size_t)(bm + row)*DIMSZ + k0 + cc*8, (void*)(As + ch*8));
            gl2lds16(BT + (size_t)(bn + row)*DIMSZ + k0 + cc*8, (void*)(Bs + ch*8));
        }
        __syncthreads();
        short8 af[4], bf[4];
        #pragma unroll
        for (int mt = 0; mt < 4; mt++) af[mt] = *(const short8*)(As + (wm*64 + mt*16 + c)*32 + g*8);
        #pragma unroll
        for (int nt = 0; nt < 4; nt++) bf[nt] = *(const short8*)(Bs + (wn*64 + nt*16 + c)*32 + g*8);
        #pragma unroll
        for (int mt = 0; mt < 4; mt++)
            #pragma unroll
            for (int nt = 0; nt < 4; nt++)
                acc[mt][nt] = MFMA16(af[mt], bf[nt], acc[mt][nt]);
    }
    #pragma unroll
    for (int mt = 0; mt < 4; mt++)
        #pragma unroll
        for (int nt = 0; nt < 4; nt++)
            #pragma unroll
            for (int r2 = 0; r2 < 4; r2++) {
                const int row = bm + wm*64 + mt*16 + g*4 + r2;
                const int col = bn + wn*64 + nt*16 + c;
                out0[(size_t)row*DIMSZ + col] = acc[mt][nt][r2];
            }
}

// ---------------------------------------------------------------------------
extern "C" void kernel_launch(void* const* d_in, const int* in_sizes, int n_in,
                              void* d_out, int out_size, void* d_ws, size_t ws_size,
                              hipStream_t stream) {
    const float* x       = (const float*)d_in[0];
    const float* vres    = (const float*)d_in[1];
    const float* gamma   = (const float*)d_in[2];
    const float* w_qkv   = (const float*)d_in[3];
    const float* w_mix   = (const float*)d_in[4];
    const float* b_mix   = (const float*)d_in[5];
    const float* w_gates = (const float*)d_in[6];
    const float* b_gates = (const float*)d_in[7];
    const float* w_out   = (const float*)d_in[8];

    float* out0 = (float*)d_out;                 // (2,2048,1024)
    float* out1 = out0 + (size_t)ROWS * DIMSZ;   // (2,16,2048,64) = original v

    char* ws = (char*)d_ws;
    unsigned short* xnb   = (unsigned short*)(ws);                    // 8 MB
    unsigned short* wqkvT = (unsigned short*)(ws + (8u<<20));         // 6 MB
    unsigned short* woutT = (unsigned short*)(ws + (14u<<20));        // 2 MB
    unsigned short* qb2   = (unsigned short*)(ws + (16u<<20));        // 8 MB
    unsigned short* kb2   = (unsigned short*)(ws + (24u<<20));        // 8 MB
    unsigned short* vT    = (unsigned short*)(ws + (32u<<20));        // 8 MB
    unsigned short* attnO = (unsigned short*)(ws + (40u<<20));        // 8 MB (= Op0)
    float*          mixb  = (float*)(ws + (48u<<20));                 // 256 KB
    float*          gatesb= (float*)(ws + (48u<<20) + 262144);        // 256 KB
    unsigned short* wmgT  = (unsigned short*)(ws + (49u<<20));        // 64 KB
    unsigned short* Op1   = (unsigned short*)(ws + (50u<<20));        // 8 MB
    float*          lpart = (float*)(ws + (58u<<20));                 // 512 KB

    transpose_all_kernel<<<dim3(129, DIMSZ/32), 256, 0, stream>>>(
        w_qkv, w_out, w_mix, w_gates, wqkvT, woutT, wmgT);

    rmsnorm_kernel<<<ROWS, 256, 0, stream>>>(x, gamma, xnb);

    mix_gates_mfma<<<ROWS/128, 256, 0, stream>>>(
        xnb, wmgT, b_mix, b_gates, mixb, gatesb);

    gemm_qkv_mfma<<<dim3(3*DIMSZ/128, ROWS/128), 256, 0, stream>>>(
        xnb, wqkvT, qb2, kb2, out1);

    rope_blend_kernel2<<<dim3(NSEQ/64, BATCH*HEADS), 256, 0, stream>>>(
        qb2, kb2, out1, vres, mixb, vT);

    attn_mfma_kernel<<<dim3(NSEQ/128, BATCH*HEADS*2), 256, 0, stream>>>(
        qb2, kb2, vT, attnO, Op1, lpart);

    attn_combine_kernel<<<ROWS*DIMSZ/8/256, 256, 0, stream>>>(
        Op1, lpart, gatesb, attnO);

    gemm_out_mfma<<<dim3(DIMSZ/128, ROWS/128), 256, 0, stream>>>(
        attnO, woutT, out0);
}